// Round 13
// baseline (723.906 us; speedup 1.0000x reference)
//
#include <hip/hip_runtime.h>
#include <hip/hip_bf16.h>
#include <hip/hip_cooperative_groups.h>
#include <cmath>
#include <cstdint>

namespace cg = cooperative_groups;

// Problem dims (fixed by reference)
constexpr int B_ = 2, C_ = 96, H_ = 96, W_ = 96, L_ = H_ * W_;   // L = 9216
constexpr int N_ = 8, R_ = 6, K_ = 4, D_ = R_ + 2 * N_;          // D = 22
constexpr int CH_ = 128, G_ = L_ / CH_;                           // 72 chunks/sequence
constexpr int JS_ = 4, SEG_ = CH_ / JS_;                          // 4 sub-segments of 32
constexpr int S_ = G_ * JS_;                                      // 288 segments/sequence
constexpr float EPS_ = 1e-5f;

__device__ __forceinline__ float silu_f(float v) { return v / (1.f + __expf(-v)); }
__device__ __forceinline__ float softplus_f(float t) {
    return fmaxf(t, 0.f) + __logf(1.f + __expf(-fabsf(t)));
}

__device__ __forceinline__ void block_reduce2(float& a, float& b) {
    #pragma unroll
    for (int o = 32; o; o >>= 1) { a += __shfl_xor(a, o); b += __shfl_xor(b, o); }
    __shared__ float la[4], lb[4];
    int wid = threadIdx.x >> 6;
    if ((threadIdx.x & 63) == 0) { la[wid] = a; lb[wid] = b; }
    __syncthreads();
    if (threadIdx.x == 0) { a = la[0] + la[1] + la[2] + la[3]; b = lb[0] + lb[1] + lb[2] + lb[3]; }
    __syncthreads();
}

__device__ __forceinline__ void block_reduce4(float& a, float& b, float& c, float& d) {
    #pragma unroll
    for (int o = 32; o; o >>= 1) {
        a += __shfl_xor(a, o); b += __shfl_xor(b, o);
        c += __shfl_xor(c, o); d += __shfl_xor(d, o);
    }
    __shared__ float ls[4][4];
    int wid = threadIdx.x >> 6;
    if ((threadIdx.x & 63) == 0) { ls[wid][0] = a; ls[wid][1] = b; ls[wid][2] = c; ls[wid][3] = d; }
    __syncthreads();
    if (threadIdx.x == 0) {
        a = ls[0][0] + ls[1][0] + ls[2][0] + ls[3][0];
        b = ls[0][1] + ls[1][1] + ls[2][1] + ls[3][1];
        c = ls[0][2] + ls[1][2] + ls[2][2] + ls[3][2];
        d = ls[0][3] + ls[1][3] + ls[2][3] + ls[3][3];
    }
    __syncthreads();
}

// Shared-memory union overlays (max = Scan3S = 41,920 B)
struct DwtS   { float in_s[50][96]; float out_s[48][97]; };
struct ProjS  { float sxp[96][24]; float red[22][4][64]; };
struct Scan1S { float u_s[48][133]; float B_s[128][12]; float T_s[128][8]; };
struct Scan2S { float as_[S_ * N_]; float bs_[S_ * N_]; };
struct Scan3S { float u_s[48][133]; float B_s[128][12]; float C_s[128][12]; float T_s[128][8]; };
struct MergeS { float t1[96][33]; float t3[96][33]; };
struct FinalS { float zz[12]; float atv; };

struct P {
    const float *x, *lng, *lnb, *p1w, *p1b, *p2w, *p2b, *dww, *dwb, *xprj,
                *dtw, *dtb, *Alog, *Dsp, *n2g, *n2b, *caw1, *cab1, *caw2, *cab2;
    float *stats, *wmt, *pq, *a, *bpre, *u, *u_t, *dts, *Bsb, *Csb,
          *carA, *carB, *hinit, *ydir, *ysum, *out;
};

__global__ __launch_bounds__(256, 2) void mono_kernel(P p) {
    cg::grid_group grid = cg::this_grid();
    __shared__ __align__(16) char smem[41984];
    const int t = threadIdx.x;
    const int GS = gridDim.x;

    // ---- Phase A: gn1 stats (864 vb) + weight-fold prep (vb 864) ----
    for (int vb = blockIdx.x; vb < 865; vb += GS) {
        if (vb < 864) {
            int bx = vb % 432, b = vb / 432;
            const float* ptr = p.x + (size_t)b * C_ * L_;
            float s = 0.f, s2 = 0.f;
            for (int i = bx * 256 + t; i < C_ * L_; i += 432 * 256) {
                float v = ptr[i];
                s += v;
                s2 = fmaf(v, v, s2);
            }
            block_reduce2(s, s2);
            if (t == 0) {
                atomicAdd(&p.stats[2 * b], s);
                atomicAdd(&p.stats[2 * b + 1], s2);
            }
        } else if (t < 192) {
            int mat = t / 96, o = t % 96;
            const float* w = (mat == 0 ? p.p1w : p.p2w) + o * C_;
            float* dst = p.wmt + ((size_t)(mat * 12 + o / 8) * C_) * 8 + (o % 8);
            float Pv = 0.f, Qv = 0.f;
            for (int c = 0; c < C_; ++c) {
                float wv = w[c];
                float g = p.lng[c];
                Pv = fmaf(p.lnb[c], wv, Pv);
                Qv = fmaf(g, wv, Qv);
                dst[c * 8] = g * wv;
            }
            p.pq[mat * 192 + o] = Pv;
            p.pq[mat * 192 + 96 + o] = Qv;
        }
        __syncthreads();
    }
    grid.sync();

    // ---- Phase B: fused gn1 + dual 1x1 conv (864 vb) ----
    for (int vb = blockIdx.x; vb < 864; vb += GS) {
        constexpr int OG = 8;
        int lx = vb % 36, by = (vb / 36) % 12, b = vb / 432;
        int o0 = by * OG;
        int l = lx * 256 + t;
        constexpr float inv = 1.f / (float)(C_ * L_);
        float mu = p.stats[2 * b] * inv;
        float var = p.stats[2 * b + 1] * inv - mu * mu;
        float rs = rsqrtf(var + EPS_);
        const float4* w1q = (const float4*)(p.wmt + ((size_t)(0 * 12 + by) * C_) * 8);
        const float4* w2q = (const float4*)(p.wmt + ((size_t)(1 * 12 + by) * C_) * 8);
        const float* xb = p.x + (size_t)b * C_ * L_ + l;
        float acc1[OG], acc2[OG];
        #pragma unroll
        for (int j = 0; j < OG; ++j) { acc1[j] = 0.f; acc2[j] = 0.f; }
        #pragma unroll 4
        for (int c = 0; c < C_; ++c) {
            float xv = xb[(size_t)c * L_];
            float4 wa = w1q[2 * c];
            float4 wb = w1q[2 * c + 1];
            float4 wc = w2q[2 * c];
            float4 wd = w2q[2 * c + 1];
            acc1[0] = fmaf(xv, wa.x, acc1[0]); acc1[1] = fmaf(xv, wa.y, acc1[1]);
            acc1[2] = fmaf(xv, wa.z, acc1[2]); acc1[3] = fmaf(xv, wa.w, acc1[3]);
            acc1[4] = fmaf(xv, wb.x, acc1[4]); acc1[5] = fmaf(xv, wb.y, acc1[5]);
            acc1[6] = fmaf(xv, wb.z, acc1[6]); acc1[7] = fmaf(xv, wb.w, acc1[7]);
            acc2[0] = fmaf(xv, wc.x, acc2[0]); acc2[1] = fmaf(xv, wc.y, acc2[1]);
            acc2[2] = fmaf(xv, wc.z, acc2[2]); acc2[3] = fmaf(xv, wc.w, acc2[3]);
            acc2[4] = fmaf(xv, wd.x, acc2[4]); acc2[5] = fmaf(xv, wd.y, acc2[5]);
            acc2[6] = fmaf(xv, wd.z, acc2[6]); acc2[7] = fmaf(xv, wd.w, acc2[7]);
        }
        float murs = mu * rs;
        #pragma unroll
        for (int j = 0; j < OG; ++j) {
            int o = o0 + j;
            size_t oo = ((size_t)(b * C_ + o)) * L_ + l;
            float be1 = p.p1b[o] + p.pq[o] - murs * p.pq[96 + o];
            float be2 = p.p2b[o] + p.pq[192 + o] - murs * p.pq[288 + o];
            p.a[oo] = silu_f(fmaf(rs, acc1[j], be1));
            p.bpre[oo] = fmaf(rs, acc2[j], be2);
        }
    }
    grid.sync();

    // ---- Phase C: depthwise 3x3 + silu + transpose (384 vb) ----
    for (int vb = blockIdx.x; vb < 384; vb += GS) {
        DwtS& S = *(DwtS*)smem;
        int stripe = vb % 2, c = (vb / 2) % 96, b = vb / 192;
        int h0 = stripe * 48;
        const float* in = p.bpre + ((size_t)(b * C_ + c)) * L_;
        for (int idx = t; idx < 50 * 96; idx += 256) {
            int r = idx / 96, w = idx % 96;
            int hh = h0 - 1 + r;
            S.in_s[r][w] = (hh >= 0 && hh < 96) ? in[hh * 96 + w] : 0.f;
        }
        __syncthreads();
        const float* kw = p.dww + c * 9;
        float k0 = kw[0], k1 = kw[1], k2 = kw[2], k3 = kw[3], k4 = kw[4],
              k5 = kw[5], k6 = kw[6], k7 = kw[7], k8 = kw[8];
        float bs = p.dwb[c];
        float* up = p.u + ((size_t)(b * C_ + c)) * L_;
        for (int idx = t; idx < 48 * 96; idx += 256) {
            int r = idx / 96, w = idx % 96;
            int ri = r + 1;
            bool wl = (w > 0), wr = (w < 95);
            float acc = bs;
            acc = fmaf(wl ? S.in_s[ri - 1][w - 1] : 0.f, k0, acc);
            acc = fmaf(S.in_s[ri - 1][w], k1, acc);
            acc = fmaf(wr ? S.in_s[ri - 1][w + 1] : 0.f, k2, acc);
            acc = fmaf(wl ? S.in_s[ri][w - 1] : 0.f, k3, acc);
            acc = fmaf(S.in_s[ri][w], k4, acc);
            acc = fmaf(wr ? S.in_s[ri][w + 1] : 0.f, k5, acc);
            acc = fmaf(wl ? S.in_s[ri + 1][w - 1] : 0.f, k6, acc);
            acc = fmaf(S.in_s[ri + 1][w], k7, acc);
            acc = fmaf(wr ? S.in_s[ri + 1][w + 1] : 0.f, k8, acc);
            float v = silu_f(acc);
            up[(h0 + r) * 96 + w] = v;
            S.out_s[r][w] = v;
        }
        __syncthreads();
        float* tp = p.u_t + ((size_t)(b * C_ + c)) * L_;
        for (int idx = t; idx < 96 * 48; idx += 256) {
            int w = idx / 48, r = idx % 48;
            tp[w * 96 + h0 + r] = S.out_s[r][w];
        }
        __syncthreads();
    }
    grid.sync();

    // ---- Phase D: projection (c-split) (1152 vb) ----
    for (int vb = blockIdx.x; vb < 1152; vb += GS) {
        ProjS& S = *(ProjS*)smem;
        int lx = vb % 144, k = (vb / 144) % 4, b = vb / 576;
        int pos = t & 63, cgp = t >> 6;
        int l = lx * 64 + pos;
        for (int i = t; i < D_ * C_; i += 256) {
            int d = i / C_, c = i % C_;
            S.sxp[c][d] = p.xprj[(k * D_ + d) * C_ + c];
        }
        __syncthreads();
        const float* src = ((k & 1) ? p.u_t : p.u) + (size_t)b * C_ * L_;
        int posIdx = (k < 2) ? l : (L_ - 1 - l);
        const float* sp = src + (size_t)(cgp * 24) * L_ + posIdx;
        float acc[D_];
        #pragma unroll
        for (int d = 0; d < D_; ++d) acc[d] = 0.f;
        #pragma unroll 4
        for (int ci = 0; ci < 24; ++ci) {
            int c = cgp * 24 + ci;
            float xv = sp[(size_t)ci * L_];
            float w[22];
            *(float4*)&w[0]  = *(const float4*)&S.sxp[c][0];
            *(float4*)&w[4]  = *(const float4*)&S.sxp[c][4];
            *(float4*)&w[8]  = *(const float4*)&S.sxp[c][8];
            *(float4*)&w[12] = *(const float4*)&S.sxp[c][12];
            *(float4*)&w[16] = *(const float4*)&S.sxp[c][16];
            *(float2*)&w[20] = *(const float2*)&S.sxp[c][20];
            #pragma unroll
            for (int d = 0; d < D_; ++d) acc[d] = fmaf(xv, w[d], acc[d]);
        }
        #pragma unroll
        for (int d = 0; d < D_; ++d) S.red[d][cgp][pos] = acc[d];
        __syncthreads();
        if (cgp == 0) {
            #pragma unroll
            for (int r = 0; r < R_; ++r) {
                float s = S.red[r][0][pos] + S.red[r][1][pos] + S.red[r][2][pos] + S.red[r][3][pos];
                p.dts[((size_t)((b * K_ + k) * R_ + r)) * L_ + l] = s;
            }
        } else if (cgp == 1) {
            #pragma unroll
            for (int n = 0; n < N_; ++n) {
                int d = R_ + n;
                float s = S.red[d][0][pos] + S.red[d][1][pos] + S.red[d][2][pos] + S.red[d][3][pos];
                p.Bsb[((size_t)((b * K_ + k) * N_ + n)) * L_ + l] = s;
            }
        } else if (cgp == 2) {
            #pragma unroll
            for (int n = 0; n < N_; ++n) {
                int d = R_ + N_ + n;
                float s = S.red[d][0][pos] + S.red[d][1][pos] + S.red[d][2][pos] + S.red[d][3][pos];
                p.Csb[((size_t)((b * K_ + k) * N_ + n)) * L_ + l] = s;
            }
        }
        __syncthreads();
    }
    grid.sync();

    // ---- Phase E: scan phase 1 (1152 vb) ----
    for (int vb = blockIdx.x; vb < 1152; vb += GS) {
        Scan1S& S = *(Scan1S*)smem;
        int gx = vb % 144, k = (vb / 144) % 4, b = vb / 576;
        int g = gx >> 1, chalf = gx & 1;
        int c0 = chalf * 48;
        const int l0 = g * CH_;
        const float* usrc = ((k & 1) ? p.u_t : p.u) + (size_t)b * C_ * L_ + (size_t)c0 * L_;
        if (k < 2) {
            for (int idx = t; idx < 48 * 32; idx += 256) {
                int c2 = idx >> 5, q = idx & 31;
                *(float4*)&S.u_s[c2][q * 4] = *(const float4*)(usrc + (size_t)c2 * L_ + l0 + q * 4);
            }
        } else {
            for (int idx = t; idx < 48 * 32; idx += 256) {
                int c2 = idx >> 5, q = idx & 31;
                float4 v = *(const float4*)(usrc + (size_t)c2 * L_ + (L_ - l0 - q * 4 - 4));
                S.u_s[c2][q * 4 + 0] = v.w; S.u_s[c2][q * 4 + 1] = v.z;
                S.u_s[c2][q * 4 + 2] = v.y; S.u_s[c2][q * 4 + 3] = v.x;
            }
        }
        const float* Bg = p.Bsb + ((size_t)(b * K_ + k)) * N_ * L_ + l0;
        for (int idx = t; idx < 8 * 32; idx += 256) {
            int n = idx >> 5, q = idx & 31;
            float4 v = *(const float4*)(Bg + (size_t)n * L_ + q * 4);
            S.B_s[q * 4 + 0][n] = v.x; S.B_s[q * 4 + 1][n] = v.y;
            S.B_s[q * 4 + 2][n] = v.z; S.B_s[q * 4 + 3][n] = v.w;
        }
        const float* Tg = p.dts + ((size_t)(b * K_ + k)) * R_ * L_ + l0;
        for (int idx = t; idx < 6 * 32; idx += 256) {
            int r = idx >> 5, q = idx & 31;
            float4 v = *(const float4*)(Tg + (size_t)r * L_ + q * 4);
            S.T_s[q * 4 + 0][r] = v.x; S.T_s[q * 4 + 1][r] = v.y;
            S.T_s[q * 4 + 2][r] = v.z; S.T_s[q * 4 + 3][r] = v.w;
        }
        __syncthreads();
        if (t < 192) {
            int cc = t % 48, j = t / 48;
            int c = c0 + cc;
            float A[N_];
            #pragma unroll
            for (int n = 0; n < N_; ++n) A[n] = -__expf(p.Alog[(k * C_ + c) * N_ + n]);
            float wdt[R_];
            #pragma unroll
            for (int r = 0; r < R_; ++r) wdt[r] = p.dtw[(k * C_ + c) * R_ + r];
            float bdt = p.dtb[k * C_ + c];
            float ap[N_], h[N_];
            #pragma unroll
            for (int n = 0; n < N_; ++n) { ap[n] = 1.f; h[n] = 0.f; }
            int i0 = j * SEG_;
            for (int ii = 0; ii < SEG_; ii += 4) {
                float4 x4 = *(float4*)&S.u_s[cc][i0 + ii];
                float xx[4] = {x4.x, x4.y, x4.z, x4.w};
                #pragma unroll
                for (int s = 0; s < 4; ++s) {
                    int i = i0 + ii + s;
                    float4 t4 = *(float4*)&S.T_s[i][0];
                    float2 t2 = *(float2*)&S.T_s[i][4];
                    float tt = bdt;
                    tt = fmaf(t4.x, wdt[0], tt); tt = fmaf(t4.y, wdt[1], tt);
                    tt = fmaf(t4.z, wdt[2], tt); tt = fmaf(t4.w, wdt[3], tt);
                    tt = fmaf(t2.x, wdt[4], tt); tt = fmaf(t2.y, wdt[5], tt);
                    float d = softplus_f(tt);
                    float dx = d * xx[s];
                    float4 ba = *(float4*)&S.B_s[i][0];
                    float4 bb = *(float4*)&S.B_s[i][4];
                    float bv[8] = {ba.x, ba.y, ba.z, ba.w, bb.x, bb.y, bb.z, bb.w};
                    #pragma unroll
                    for (int n = 0; n < N_; ++n) {
                        float da = __expf(d * A[n]);
                        ap[n] *= da;
                        h[n] = fmaf(da, h[n], bv[n] * dx);
                    }
                }
            }
            size_t sidx = (((size_t)((b * K_ + k) * C_ + c)) * S_ + (g * JS_ + j)) * N_;
            #pragma unroll
            for (int n = 0; n < N_; ++n) { p.carA[sidx + n] = ap[n]; p.carB[sidx + n] = h[n]; }
        }
        __syncthreads();
    }
    grid.sync();

    // ---- Phase F: hierarchical carry scan (768 vb) ----
    for (int vb = blockIdx.x; vb < 768; vb += GS) {
        Scan2S& S = *(Scan2S*)smem;
        int row = vb;
        const float4* Ag = (const float4*)(p.carA + (size_t)row * S_ * N_);
        const float4* Bg4 = (const float4*)(p.carB + (size_t)row * S_ * N_);
        float4* As4 = (float4*)S.as_;
        float4* Bs4 = (float4*)S.bs_;
        for (int i = t; i < S_ * N_ / 4; i += 256) { As4[i] = Ag[i]; Bs4[i] = Bg4[i]; }
        __syncthreads();
        int n = t >> 5, g = t & 31;
        int s0 = g * 9;
        float A = 1.f, Bc = 0.f;
        #pragma unroll
        for (int q = 0; q < 9; ++q) {
            int idx = (s0 + q) * N_ + n;
            float a = S.as_[idx], b = S.bs_[idx];
            Bc = fmaf(a, Bc, b);
            A = a * A;
        }
        #pragma unroll
        for (int d = 1; d < 32; d <<= 1) {
            float pA = __shfl_up(A, d, 32);
            float pB = __shfl_up(Bc, d, 32);
            if (g >= d) { Bc = fmaf(A, pB, Bc); A = A * pA; }
        }
        float h = __shfl_up(Bc, 1, 32);
        if (g == 0) h = 0.f;
        #pragma unroll
        for (int q = 0; q < 9; ++q) {
            int idx = (s0 + q) * N_ + n;
            float a = S.as_[idx], b = S.bs_[idx];
            S.as_[idx] = h;
            h = fmaf(a, h, b);
        }
        __syncthreads();
        float4* Hg = (float4*)(p.hinit + (size_t)row * S_ * N_);
        for (int i = t; i < S_ * N_ / 4; i += 256) Hg[i] = As4[i];
        __syncthreads();
    }
    grid.sync();

    // ---- Phase G: scan phase 3 (1152 vb) ----
    for (int vb = blockIdx.x; vb < 1152; vb += GS) {
        Scan3S& S = *(Scan3S*)smem;
        int gx = vb % 144, k = (vb / 144) % 4, b = vb / 576;
        int g = gx >> 1, chalf = gx & 1;
        int c0 = chalf * 48;
        const int l0 = g * CH_;
        const float* usrc = ((k & 1) ? p.u_t : p.u) + (size_t)b * C_ * L_ + (size_t)c0 * L_;
        if (k < 2) {
            for (int idx = t; idx < 48 * 32; idx += 256) {
                int c2 = idx >> 5, q = idx & 31;
                *(float4*)&S.u_s[c2][q * 4] = *(const float4*)(usrc + (size_t)c2 * L_ + l0 + q * 4);
            }
        } else {
            for (int idx = t; idx < 48 * 32; idx += 256) {
                int c2 = idx >> 5, q = idx & 31;
                float4 v = *(const float4*)(usrc + (size_t)c2 * L_ + (L_ - l0 - q * 4 - 4));
                S.u_s[c2][q * 4 + 0] = v.w; S.u_s[c2][q * 4 + 1] = v.z;
                S.u_s[c2][q * 4 + 2] = v.y; S.u_s[c2][q * 4 + 3] = v.x;
            }
        }
        const float* Bg = p.Bsb + ((size_t)(b * K_ + k)) * N_ * L_ + l0;
        const float* Cg = p.Csb + ((size_t)(b * K_ + k)) * N_ * L_ + l0;
        for (int idx = t; idx < 8 * 32; idx += 256) {
            int n = idx >> 5, q = idx & 31;
            float4 v = *(const float4*)(Bg + (size_t)n * L_ + q * 4);
            S.B_s[q * 4 + 0][n] = v.x; S.B_s[q * 4 + 1][n] = v.y;
            S.B_s[q * 4 + 2][n] = v.z; S.B_s[q * 4 + 3][n] = v.w;
            float4 w = *(const float4*)(Cg + (size_t)n * L_ + q * 4);
            S.C_s[q * 4 + 0][n] = w.x; S.C_s[q * 4 + 1][n] = w.y;
            S.C_s[q * 4 + 2][n] = w.z; S.C_s[q * 4 + 3][n] = w.w;
        }
        const float* Tg = p.dts + ((size_t)(b * K_ + k)) * R_ * L_ + l0;
        for (int idx = t; idx < 6 * 32; idx += 256) {
            int r = idx >> 5, q = idx & 31;
            float4 v = *(const float4*)(Tg + (size_t)r * L_ + q * 4);
            S.T_s[q * 4 + 0][r] = v.x; S.T_s[q * 4 + 1][r] = v.y;
            S.T_s[q * 4 + 2][r] = v.z; S.T_s[q * 4 + 3][r] = v.w;
        }
        __syncthreads();
        if (t < 192) {
            int cc = t % 48, j = t / 48;
            int c = c0 + cc;
            float A[N_];
            #pragma unroll
            for (int n = 0; n < N_; ++n) A[n] = -__expf(p.Alog[(k * C_ + c) * N_ + n]);
            float wdt[R_];
            #pragma unroll
            for (int r = 0; r < R_; ++r) wdt[r] = p.dtw[(k * C_ + c) * R_ + r];
            float bdt = p.dtb[k * C_ + c];
            float Dv = p.Dsp[k * C_ + c];
            float h[N_];
            size_t sidx = (((size_t)((b * K_ + k) * C_ + c)) * S_ + (g * JS_ + j)) * N_;
            #pragma unroll
            for (int n = 0; n < N_; ++n) h[n] = p.hinit[sidx + n];
            int i0 = j * SEG_;
            for (int ii = 0; ii < SEG_; ii += 4) {
                float4 x4 = *(float4*)&S.u_s[cc][i0 + ii];
                float xx[4] = {x4.x, x4.y, x4.z, x4.w};
                #pragma unroll
                for (int s = 0; s < 4; ++s) {
                    int i = i0 + ii + s;
                    float4 t4 = *(float4*)&S.T_s[i][0];
                    float2 t2 = *(float2*)&S.T_s[i][4];
                    float tt = bdt;
                    tt = fmaf(t4.x, wdt[0], tt); tt = fmaf(t4.y, wdt[1], tt);
                    tt = fmaf(t4.z, wdt[2], tt); tt = fmaf(t4.w, wdt[3], tt);
                    tt = fmaf(t2.x, wdt[4], tt); tt = fmaf(t2.y, wdt[5], tt);
                    float d = softplus_f(tt);
                    float dx = d * xx[s];
                    float4 ba = *(float4*)&S.B_s[i][0];
                    float4 bb = *(float4*)&S.B_s[i][4];
                    float4 ca = *(float4*)&S.C_s[i][0];
                    float4 cb = *(float4*)&S.C_s[i][4];
                    float bv[8] = {ba.x, ba.y, ba.z, ba.w, bb.x, bb.y, bb.z, bb.w};
                    float cv[8] = {ca.x, ca.y, ca.z, ca.w, cb.x, cb.y, cb.z, cb.w};
                    float y = Dv * xx[s];
                    #pragma unroll
                    for (int n = 0; n < N_; ++n) {
                        float da = __expf(d * A[n]);
                        h[n] = fmaf(da, h[n], bv[n] * dx);
                        y = fmaf(cv[n], h[n], y);
                    }
                    S.u_s[cc][i] = y;
                }
            }
        }
        __syncthreads();
        float* yg = p.ydir + ((size_t)((b * K_ + k) * C_ + c0)) * L_ + l0;
        for (int idx = t; idx < 48 * 32; idx += 256) {
            int c2 = idx >> 5, q = idx & 31;
            *(float4*)(yg + (size_t)c2 * L_ + q * 4) = *(float4*)&S.u_s[c2][q * 4];
        }
        __syncthreads();
    }
    grid.sync();

    // ---- Phase H: merge 4 planes + gn2 stats + gating moments (576 vb) ----
    for (int vb = blockIdx.x; vb < 576; vb += GS) {
        MergeS& S = *(MergeS*)smem;
        int hx = vb % 3, c = (vb / 3) % 96, b = vb / 288;
        int h0 = hx * 32;
        const float* y0p = p.ydir + ((size_t)((b * K_ + 0) * C_ + c)) * L_;
        const float* y1p = p.ydir + ((size_t)((b * K_ + 1) * C_ + c)) * L_;
        const float* y2p = p.ydir + ((size_t)((b * K_ + 2) * C_ + c)) * L_;
        const float* y3p = p.ydir + ((size_t)((b * K_ + 3) * C_ + c)) * L_;
        for (int idx = t; idx < 96 * 32; idx += 256) {
            int w = idx >> 5, hh = idx & 31;
            S.t1[w][hh] = y1p[w * 96 + h0 + hh];
            S.t3[w][hh] = y3p[L_ - 1 - (w * 96 + h0 + hh)];
        }
        __syncthreads();
        float s = 0.f, s2 = 0.f, m0 = 0.f, m1 = 0.f;
        float* yout = p.ysum + ((size_t)(b * C_ + c)) * L_;
        const float* ap = p.a + ((size_t)(b * C_ + c)) * L_;
        for (int idx = t; idx < 32 * 96; idx += 256) {
            int hh = idx / 96, w = idx % 96;
            int pix = (h0 + hh) * 96 + w;
            float v = y0p[pix] + y2p[L_ - 1 - pix] + S.t1[w][hh] + S.t3[w][hh];
            float av = ap[pix];
            yout[pix] = v;
            s += v;
            s2 = fmaf(v, v, s2);
            m0 += av;
            m1 = fmaf(av, v, m1);
        }
        block_reduce4(s, s2, m0, m1);
        if (t == 0) {
            atomicAdd(&p.stats[4 + 2 * b], s);
            atomicAdd(&p.stats[5 + 2 * b], s2);
            atomicAdd(&p.stats[16 + b * C_ + c], m0);
            atomicAdd(&p.stats[256 + b * C_ + c], m1);
        }
        __syncthreads();
    }
    grid.sync();

    // ---- Phase J: SE-attn (recomputed per block) + gn2 + gate + residual (6912 vb) ----
    for (int vb = blockIdx.x; vb < 6912; vb += GS) {
        FinalS& S = *(FinalS*)smem;
        int lx = vb % 36, c = (vb / 36) % 96, b = vb / 3456;
        int pix = lx * 256 + t;
        constexpr float inv = 1.f / (float)(C_ * L_);
        float mu = p.stats[4 + 2 * b] * inv;
        float var = p.stats[5 + 2 * b] * inv - mu * mu;
        float rs = rsqrtf(var + EPS_);
        if (t < 12) {
            float acc = p.cab1[t];
            for (int cc = 0; cc < C_; ++cc) {
                float M0 = p.stats[16 + b * C_ + cc];
                float M1 = p.stats[256 + b * C_ + cc];
                float ss = (p.n2g[cc] * rs * (M1 - mu * M0) + p.n2b[cc] * M0) * (1.f / (float)L_);
                acc = fmaf(p.caw1[t * C_ + cc], ss, acc);
            }
            S.zz[t] = fmaxf(acc, 0.f);
        }
        __syncthreads();
        if (t == 0) {
            float acc = p.cab2[c];
            #pragma unroll
            for (int j = 0; j < 12; ++j) acc = fmaf(p.caw2[c * 12 + j], S.zz[j], acc);
            S.atv = 1.f / (1.f + __expf(-acc));
        }
        __syncthreads();
        float at = S.atv;
        float gc = p.n2g[c] * rs, bc = p.n2b[c] - mu * rs * p.n2g[c];
        size_t o = ((size_t)(b * C_ + c)) * L_ + pix;
        float bn = fmaf(p.ysum[o], gc, bc);
        p.out[o] = fmaf(p.a[o] * bn, at, p.x[o]);
        __syncthreads();
    }
}

extern "C" void kernel_launch(void* const* d_in, const int* in_sizes, int n_in,
                              void* d_out, int out_size, void* d_ws, size_t ws_size,
                              hipStream_t stream) {
    const size_t BCL = (size_t)B_ * C_ * L_ * sizeof(float);
    char* ws = (char*)d_ws;
    size_t off = 0;
    float* stats = (float*)(ws + off); off += 4096;
    float* wmt   = (float*)(ws + off); off += 2 * 12 * 96 * 8 * sizeof(float);
    float* pq    = (float*)(ws + off); off += 2 * 2 * 96 * sizeof(float);
    float* a     = (float*)(ws + off); off += BCL;
    float* bpre  = (float*)(ws + off); off += BCL;      // carA overlays
    float* u     = (float*)(ws + off); off += BCL;      // ysum overlays after scan3
    float* u_t   = (float*)(ws + off); off += BCL;
    float* dts   = (float*)(ws + off); off += (size_t)B_ * K_ * R_ * L_ * sizeof(float);
    float* Bsb   = (float*)(ws + off); off += (size_t)B_ * K_ * N_ * L_ * sizeof(float);
    float* Csb   = (float*)(ws + off); off += (size_t)B_ * K_ * N_ * L_ * sizeof(float);
    float* carB  = (float*)(ws + off); off += (size_t)B_ * K_ * C_ * S_ * N_ * sizeof(float);
    float* hinit = (float*)(ws + off); off += (size_t)B_ * K_ * C_ * S_ * N_ * sizeof(float);
    float* ydir  = (float*)(ws + off); off += (size_t)B_ * K_ * C_ * L_ * sizeof(float);

    P prm;
    prm.x    = (const float*)d_in[0];
    prm.lng  = (const float*)d_in[1];
    prm.lnb  = (const float*)d_in[2];
    prm.p1w  = (const float*)d_in[3];
    prm.p1b  = (const float*)d_in[4];
    prm.p2w  = (const float*)d_in[5];
    prm.p2b  = (const float*)d_in[6];
    prm.dww  = (const float*)d_in[7];
    prm.dwb  = (const float*)d_in[8];
    prm.xprj = (const float*)d_in[9];
    prm.dtw  = (const float*)d_in[10];
    prm.dtb  = (const float*)d_in[11];
    prm.Alog = (const float*)d_in[12];
    prm.Dsp  = (const float*)d_in[13];
    prm.n2g  = (const float*)d_in[14];
    prm.n2b  = (const float*)d_in[15];
    prm.caw1 = (const float*)d_in[16];
    prm.cab1 = (const float*)d_in[17];
    prm.caw2 = (const float*)d_in[18];
    prm.cab2 = (const float*)d_in[19];
    prm.stats = stats; prm.wmt = wmt; prm.pq = pq;
    prm.a = a; prm.bpre = bpre; prm.u = u; prm.u_t = u_t;
    prm.dts = dts; prm.Bsb = Bsb; prm.Csb = Csb;
    prm.carA = bpre;    // bpre dead after dwt phase
    prm.carB = carB; prm.hinit = hinit; prm.ydir = ydir;
    prm.ysum = u;       // u dead after scan3 phase
    prm.out = (float*)d_out;

    // Runtime-correct cooperative grid: query actual co-residency instead of
    // assuming 2 blocks/CU (R11's failure: hard-coded 512 > max co-resident).
    int dev = 0;
    hipGetDevice(&dev);
    int cus = 256;
    hipDeviceGetAttribute(&cus, hipDeviceAttributeMultiprocessorCount, dev);
    int nb = 0;
    hipOccupancyMaxActiveBlocksPerMultiprocessor(&nb, mono_kernel, 256, 0);
    if (nb < 1) nb = 1;
    long long grid_ll = (long long)nb * (long long)cus;
    int grid = (grid_ll > 1024) ? 1024 : (int)grid_ll;
    if (grid < 64) grid = 64;

    hipMemsetAsync(stats, 0, 4096, stream);
    void* args[] = { &prm };
    hipLaunchCooperativeKernel((const void*)mono_kernel, dim3(grid), dim3(256),
                               args, 0, stream);
}